// Round 5
// baseline (316.259 us; speedup 1.0000x reference)
//
#include <hip/hip_runtime.h>
#include <math.h>

#define D_MODEL 96
#define D_STATE 16
#define IMG 32
#define NUM_V 5
#define GROUPS 4
#define BATCH 4
#define HW (IMG*IMG)                    // 1024
#define CPG (D_MODEL/GROUPS)            // 24
#define NCOEF (D_MODEL + 2*D_STATE)     // 128: [0,96)=delta, [96,112)=B, [112,128)=C
#define Y_SIZE (BATCH*NUM_V*D_MODEL*HW) // 1966080

typedef float f32x4 __attribute__((ext_vector_type(4)));

__device__ __forceinline__ void nt_store4(const float4& v, float4* p) {
    f32x4 tmp = {v.x, v.y, v.z, v.w};
    __builtin_nontemporal_store(tmp, (f32x4*)p);
}

// ---------------- GroupNorm (float4) ----------------
__global__ __launch_bounds__(256) void gn_kernel(const float4* __restrict__ u4,
                                                 const float* __restrict__ gamma,
                                                 const float* __restrict__ beta,
                                                 float4* __restrict__ unorm4) {
    int b = blockIdx.x >> 2, g = blockIdx.x & 3;
    int t = threadIdx.x;
    const int base4 = ((b * D_MODEL + g * CPG) * HW) >> 2;
    const int n4 = (CPG * HW) >> 2;  // 6144 float4s
    float s = 0.f, s2 = 0.f;
    for (int k = t; k < n4; k += 256) {
        float4 v = u4[base4 + k];
        s += v.x + v.y + v.z + v.w;
        s2 = fmaf(v.x, v.x, fmaf(v.y, v.y, fmaf(v.z, v.z, fmaf(v.w, v.w, s2))));
    }
    for (int off = 32; off; off >>= 1) {
        s  += __shfl_down(s,  off);
        s2 += __shfl_down(s2, off);
    }
    __shared__ float red[8];
    int wid = t >> 6;
    if ((t & 63) == 0) { red[wid * 2] = s; red[wid * 2 + 1] = s2; }
    __syncthreads();
    if (t == 0) {
        float S = 0.f, S2 = 0.f;
        for (int i = 0; i < 4; ++i) { S += red[i * 2]; S2 += red[i * 2 + 1]; }
        float nf = (float)(CPG * HW);
        float mu  = S / nf;
        float var = S2 / nf - mu * mu;
        red[0] = mu;
        red[1] = rsqrtf(var + 1e-5f);
    }
    __syncthreads();
    float mu = red[0], rs = red[1];
    for (int k = t; k < n4; k += 256) {
        int c = g * CPG + (k >> 8);           // 256 float4 per channel
        float ga = gamma[c] * rs, be = beta[c] - mu * gamma[c] * rs;
        float4 v = u4[base4 + k];
        float4 o;
        o.x = fmaf(v.x, ga, be); o.y = fmaf(v.y, ga, be);
        o.z = fmaf(v.z, ga, be); o.w = fmaf(v.w, ga, be);
        unorm4[base4 + k] = o;
    }
}

// ---------------- circular 3x3 convs (float4, 4 pixels/thread) ----------------
__global__ __launch_bounds__(256) void conv_kernel(const float4* __restrict__ unorm4,
                                                   const float* __restrict__ w_delta,
                                                   const float* __restrict__ b_delta,
                                                   const float* __restrict__ w_B,
                                                   const float* __restrict__ w_C,
                                                   const float* __restrict__ dt_ptr,
                                                   float4* __restrict__ coef4) {
    int bid = blockIdx.x;             // 512 = BATCH * NCOEF
    int b  = bid >> 7;
    int oc = bid & 127;
    int t  = threadIdx.x;
    int h  = t >> 3;                  // 0..31
    int j  = t & 7;                   // quad index in row
    int lane = t & 63;
    int ll = (lane & 56) | ((j + 7) & 7);
    int rl = (lane & 56) | ((j + 1) & 7);

    const float* wp;
    float bias;
    bool is_delta = false;
    if (oc < D_MODEL) {
        wp = w_delta + oc * D_MODEL * 9;
        bias = b_delta[oc] + dt_ptr[0];
        is_delta = true;
    } else if (oc < D_MODEL + D_STATE) {
        wp = w_B + (oc - D_MODEL) * D_MODEL * 9;
        bias = 0.f;
    } else {
        wp = w_C + (oc - D_MODEL - D_STATE) * D_MODEL * 9;
        bias = 0.f;
    }
    const float4* ub4 = unorm4 + ((b * D_MODEL * HW) >> 2);

    float4 acc = {bias, bias, bias, bias};
    int hm = (h + 31) & 31, hp = (h + 1) & 31;
    int ro[3] = {hm * 8 + j, h * 8 + j, hp * 8 + j};   // float4 row offsets

    for (int ic = 0; ic < D_MODEL; ++ic) {
        const float* wr = wp + ic * 9;
        const int icb = ic * 256;
        #pragma unroll
        for (int kh = 0; kh < 3; ++kh) {
            float4 q = ub4[icb + ro[kh]];
            float lw = __shfl(q.w, ll);
            float rx = __shfl(q.x, rl);
            float wa = wr[kh * 3 + 0], wb = wr[kh * 3 + 1], wc = wr[kh * 3 + 2];
            acc.x = fmaf(wa, lw,  fmaf(wb, q.x, fmaf(wc, q.y, acc.x)));
            acc.y = fmaf(wa, q.x, fmaf(wb, q.y, fmaf(wc, q.z, acc.y)));
            acc.z = fmaf(wa, q.y, fmaf(wb, q.z, fmaf(wc, q.w, acc.z)));
            acc.w = fmaf(wa, q.z, fmaf(wb, q.w, fmaf(wc, rx,  acc.w)));
        }
    }
    if (is_delta) {
        float* a = (float*)&acc;
        #pragma unroll
        for (int k = 0; k < 4; ++k) {
            float x = a[k];
            float sp = x > 20.f ? x : log1pf(__expf(x));
            a[k] = fminf(fmaxf(sp, 1e-4f), 5.f);
        }
    }
    coef4[((b * NCOEF + oc) * HW >> 2) + h * 8 + j] = acc;
}

// ---------------- state update: one block per (b, direction, d) ----------------
// 1920 blocks x 256 thr = 30 waves/CU; 16 independent n-iterations per thread
__global__ __launch_bounds__(256) void state_kernel(const float4* __restrict__ u4,
                                                    const float4* __restrict__ s_prev4,
                                                    const float4* __restrict__ coef4,
                                                    const float* __restrict__ log_A,
                                                    const float* __restrict__ D_param,
                                                    float4* __restrict__ out4) {
    int bid = blockIdx.x;                       // B * NUM_V * D_MODEL = 1920
    int b = bid / (NUM_V * D_MODEL);
    int r = bid - b * (NUM_V * D_MODEL);
    int i = r / D_MODEL;
    int d = r - i * D_MODEL;

    int t = threadIdx.x;                        // 0..255 = full plane of float4s
    int h = t >> 3;                             // 0..31
    int j = t & 7;
    int lane = t & 63;
    int ll = (lane & 56) | ((j + 7) & 7);       // lane holding col w-1 edge
    int rl = (lane & 56) | ((j + 1) & 7);       // lane holding col w+1 edge
    int hw4 = t;

    // source float4 offset within plane for this direction
    // i=0: none; i=1 (vw=+1): col shift via shuffle; i=2 (vw=-1): col shift;
    // i=3 (vh=+1): row h-1;   i=4 (vh=-1): row h+1
    int src4 = hw4;
    if (i == 3) src4 = (((h + 31) & 31) << 3) | j;
    if (i == 4) src4 = (((h + 1) & 31) << 3) | j;
    const int mode = (i == 1) ? 1 : (i == 2) ? 2 : 0;

    float4 delta = coef4[((b * NCOEF + d) * HW >> 2) + hw4];
    float4 u     = u4[((b * D_MODEL + d) * HW >> 2) + hw4];
    float Dp     = D_param[d];
    const float* lA = log_A + d * D_STATE;

    const long pb = (long)((b * NUM_V + i) * D_MODEL + d) * (D_STATE * HW / 4);
    const float4* sp = s_prev4 + pb;
    float4* outs = out4 + (Y_SIZE >> 2) + pb;
    const float4* Bp = coef4 + ((b * NCOEF + D_MODEL) * HW >> 2) + hw4;
    const float4* Cp = coef4 + ((b * NCOEF + D_MODEL + D_STATE) * HW >> 2) + hw4;

    float4 y = {0.f, 0.f, 0.f, 0.f};

    #pragma unroll 4
    for (int n = 0; n < D_STATE; ++n) {
        int n4 = n * (HW / 4);
        float4 Bv = Bp[n4];
        float4 Cv = Cp[n4];
        float4 q  = sp[n4 + src4];
        float A = -__expf(lA[n]);
        float4 Ab, bu;
        Ab.x = __expf(delta.x * A); Ab.y = __expf(delta.y * A);
        Ab.z = __expf(delta.z * A); Ab.w = __expf(delta.w * A);
        bu.x = delta.x * Bv.x * u.x; bu.y = delta.y * Bv.y * u.y;
        bu.z = delta.z * Bv.z * u.z; bu.w = delta.w * Bv.w * u.w;

        float4 s = q;
        if (mode == 1) {                 // src col w-1
            float lw = __shfl(q.w, ll);
            s.x = lw; s.y = q.x; s.z = q.y; s.w = q.z;
        } else if (mode == 2) {          // src col w+1
            float rx = __shfl(q.x, rl);
            s.x = q.y; s.y = q.z; s.z = q.w; s.w = rx;
        }

        float4 sn;
        sn.x = fmaf(Ab.x, s.x, bu.x); sn.y = fmaf(Ab.y, s.y, bu.y);
        sn.z = fmaf(Ab.z, s.z, bu.z); sn.w = fmaf(Ab.w, s.w, bu.w);
        nt_store4(sn, &outs[n4 + hw4]);
        y.x = fmaf(sn.x, Cv.x, y.x); y.y = fmaf(sn.y, Cv.y, y.y);
        y.z = fmaf(sn.z, Cv.z, y.z); y.w = fmaf(sn.w, Cv.w, y.w);
    }

    float4 o;
    o.x = fmaf(u.x, Dp, y.x); o.y = fmaf(u.y, Dp, y.y);
    o.z = fmaf(u.z, Dp, y.z); o.w = fmaf(u.w, Dp, y.w);
    out4[(((b * NUM_V + i) * D_MODEL + d) * HW >> 2) + hw4] = o;
}

extern "C" void kernel_launch(void* const* d_in, const int* in_sizes, int n_in,
                              void* d_out, int out_size, void* d_ws, size_t ws_size,
                              hipStream_t stream) {
    const float* u_t     = (const float*)d_in[0];
    const float* s_prev  = (const float*)d_in[1];
    const float* gamma   = (const float*)d_in[2];
    const float* beta    = (const float*)d_in[3];
    const float* w_delta = (const float*)d_in[4];
    const float* b_delta = (const float*)d_in[5];
    const float* w_B     = (const float*)d_in[6];
    const float* w_C     = (const float*)d_in[7];
    const float* log_A   = (const float*)d_in[8];
    const float* D_param = (const float*)d_in[9];
    const float* dt_ptr  = (const float*)d_in[10];
    float* out = (float*)d_out;

    float* unorm = (float*)d_ws;                       // BATCH*96*1024 floats
    float* coef  = unorm + BATCH * D_MODEL * HW;       // BATCH*128*1024 floats

    hipLaunchKernelGGL(gn_kernel, dim3(BATCH * GROUPS), dim3(256), 0, stream,
                       (const float4*)u_t, gamma, beta, (float4*)unorm);
    hipLaunchKernelGGL(conv_kernel, dim3(BATCH * NCOEF), dim3(256), 0, stream,
                       (const float4*)unorm, w_delta, b_delta, w_B, w_C, dt_ptr,
                       (float4*)coef);
    hipLaunchKernelGGL(state_kernel, dim3(BATCH * NUM_V * D_MODEL), dim3(256), 0, stream,
                       (const float4*)u_t, (const float4*)s_prev, (const float4*)coef,
                       log_A, D_param, (float4*)out);
}

// Round 6
// 312.224 us; speedup vs baseline: 1.0129x; 1.0129x over previous
//
#include <hip/hip_runtime.h>
#include <math.h>

#define D_MODEL 96
#define D_STATE 16
#define IMG 32
#define NUM_V 5
#define GROUPS 4
#define BATCH 4
#define HW (IMG*IMG)                    // 1024
#define CPG (D_MODEL/GROUPS)            // 24
#define NCOEF (D_MODEL + 2*D_STATE)     // 128: [0,96)=delta, [96,112)=B, [112,128)=C
#define Y_SIZE (BATCH*NUM_V*D_MODEL*HW) // 1966080

typedef float f32x4 __attribute__((ext_vector_type(4)));

__device__ __forceinline__ void nt_store4(const float4& v, float4* p) {
    f32x4 tmp = {v.x, v.y, v.z, v.w};
    __builtin_nontemporal_store(tmp, (f32x4*)p);
}

// ---------------- GroupNorm (float4) ----------------
__global__ __launch_bounds__(256) void gn_kernel(const float4* __restrict__ u4,
                                                 const float* __restrict__ gamma,
                                                 const float* __restrict__ beta,
                                                 float4* __restrict__ unorm4) {
    int b = blockIdx.x >> 2, g = blockIdx.x & 3;
    int t = threadIdx.x;
    const int base4 = ((b * D_MODEL + g * CPG) * HW) >> 2;
    const int n4 = (CPG * HW) >> 2;  // 6144 float4s
    float s = 0.f, s2 = 0.f;
    for (int k = t; k < n4; k += 256) {
        float4 v = u4[base4 + k];
        s += v.x + v.y + v.z + v.w;
        s2 = fmaf(v.x, v.x, fmaf(v.y, v.y, fmaf(v.z, v.z, fmaf(v.w, v.w, s2))));
    }
    for (int off = 32; off; off >>= 1) {
        s  += __shfl_down(s,  off);
        s2 += __shfl_down(s2, off);
    }
    __shared__ float red[8];
    int wid = t >> 6;
    if ((t & 63) == 0) { red[wid * 2] = s; red[wid * 2 + 1] = s2; }
    __syncthreads();
    if (t == 0) {
        float S = 0.f, S2 = 0.f;
        for (int i = 0; i < 4; ++i) { S += red[i * 2]; S2 += red[i * 2 + 1]; }
        float nf = (float)(CPG * HW);
        float mu  = S / nf;
        float var = S2 / nf - mu * mu;
        red[0] = mu;
        red[1] = rsqrtf(var + 1e-5f);
    }
    __syncthreads();
    float mu = red[0], rs = red[1];
    for (int k = t; k < n4; k += 256) {
        int c = g * CPG + (k >> 8);           // 256 float4 per channel
        float ga = gamma[c] * rs, be = beta[c] - mu * gamma[c] * rs;
        float4 v = u4[base4 + k];
        float4 o;
        o.x = fmaf(v.x, ga, be); o.y = fmaf(v.y, ga, be);
        o.z = fmaf(v.z, ga, be); o.w = fmaf(v.w, ga, be);
        unorm4[base4 + k] = o;
    }
}

// ---------------- circular 3x3 convs (float4, 4 pixels/thread) ----------------
__global__ __launch_bounds__(256) void conv_kernel(const float4* __restrict__ unorm4,
                                                   const float* __restrict__ w_delta,
                                                   const float* __restrict__ b_delta,
                                                   const float* __restrict__ w_B,
                                                   const float* __restrict__ w_C,
                                                   const float* __restrict__ dt_ptr,
                                                   float4* __restrict__ coef4) {
    int bid = blockIdx.x;             // 512 = BATCH * NCOEF
    int b  = bid >> 7;
    int oc = bid & 127;
    int t  = threadIdx.x;
    int h  = t >> 3;                  // 0..31
    int j  = t & 7;                   // quad index in row
    int lane = t & 63;
    int ll = (lane & 56) | ((j + 7) & 7);
    int rl = (lane & 56) | ((j + 1) & 7);

    const float* wp;
    float bias;
    bool is_delta = false;
    if (oc < D_MODEL) {
        wp = w_delta + oc * D_MODEL * 9;
        bias = b_delta[oc] + dt_ptr[0];
        is_delta = true;
    } else if (oc < D_MODEL + D_STATE) {
        wp = w_B + (oc - D_MODEL) * D_MODEL * 9;
        bias = 0.f;
    } else {
        wp = w_C + (oc - D_MODEL - D_STATE) * D_MODEL * 9;
        bias = 0.f;
    }
    const float4* ub4 = unorm4 + ((b * D_MODEL * HW) >> 2);

    float4 acc = {bias, bias, bias, bias};
    int hm = (h + 31) & 31, hp = (h + 1) & 31;
    int ro[3] = {hm * 8 + j, h * 8 + j, hp * 8 + j};   // float4 row offsets

    for (int ic = 0; ic < D_MODEL; ++ic) {
        const float* wr = wp + ic * 9;
        const int icb = ic * 256;
        #pragma unroll
        for (int kh = 0; kh < 3; ++kh) {
            float4 q = ub4[icb + ro[kh]];
            float lw = __shfl(q.w, ll);
            float rx = __shfl(q.x, rl);
            float wa = wr[kh * 3 + 0], wb = wr[kh * 3 + 1], wc = wr[kh * 3 + 2];
            acc.x = fmaf(wa, lw,  fmaf(wb, q.x, fmaf(wc, q.y, acc.x)));
            acc.y = fmaf(wa, q.x, fmaf(wb, q.y, fmaf(wc, q.z, acc.y)));
            acc.z = fmaf(wa, q.y, fmaf(wb, q.z, fmaf(wc, q.w, acc.z)));
            acc.w = fmaf(wa, q.z, fmaf(wb, q.w, fmaf(wc, rx,  acc.w)));
        }
    }
    if (is_delta) {
        float* a = (float*)&acc;
        #pragma unroll
        for (int k = 0; k < 4; ++k) {
            float x = a[k];
            float sp = x > 20.f ? x : log1pf(__expf(x));
            a[k] = fminf(fmaxf(sp, 1e-4f), 5.f);
        }
    }
    coef4[((b * NCOEF + oc) * HW >> 2) + h * 8 + j] = acc;
}

// ---------------- state update: block per (b,d,half-plane), deep MLP ----------------
// 768 blocks x 128 thr = 3 blocks/CU. All 5 dirs + 16 n per thread; n chunked by 8;
// per direction 16 loads batched into distinct regs. launch_bounds(128,2) -> <=256 VGPR.
__global__ __launch_bounds__(128, 2) void state_kernel(const float4* __restrict__ u4,
                                                       const float4* __restrict__ s_prev4,
                                                       const float4* __restrict__ coef4,
                                                       const float* __restrict__ log_A,
                                                       const float* __restrict__ D_param,
                                                       float4* __restrict__ out4) {
    int bid  = blockIdx.x;              // B*D*2 = 768
    int half = bid & 1;
    int bd   = bid >> 1;                // 0..383
    int b = bd / D_MODEL;
    int d = bd - b * D_MODEL;

    int t   = threadIdx.x;              // 0..127
    int hw4 = half * 128 + t;           // float4 index within plane (0..255)
    int h   = hw4 >> 3;
    int j   = t & 7;
    int lane = t & 63;
    int ll = (lane & 56) | ((j + 7) & 7);     // lane holding col w-1 edge
    int rl = (lane & 56) | ((j + 1) & 7);     // lane holding col w+1 edge
    int up4 = (((h + 31) & 31) << 3) | j;     // plane offset of row h-1 (dir vh=+1)
    int dn4 = (((h + 1) & 31) << 3) | j;      // plane offset of row h+1 (dir vh=-1)

    float4 delta = coef4[(b * NCOEF + d) * 256 + hw4];
    float4 u     = u4[(b * D_MODEL + d) * 256 + hw4];
    float Dp     = D_param[d];
    const float* lA = log_A + d * D_STATE;

    const float4* Bp = coef4 + (b * NCOEF + D_MODEL) * 256 + hw4;            // + n*256
    const float4* Cp = coef4 + (b * NCOEF + D_MODEL + D_STATE) * 256 + hw4;  // + n*256

    long sbase[NUM_V];
    #pragma unroll
    for (int i = 0; i < NUM_V; ++i)
        sbase[i] = (long)((b * NUM_V + i) * D_MODEL + d) * (D_STATE * 256);

    float4* outs = out4 + (Y_SIZE >> 2);
    float4 y[NUM_V];
    #pragma unroll
    for (int i = 0; i < NUM_V; ++i) y[i] = (float4){0.f, 0.f, 0.f, 0.f};

    #pragma unroll
    for (int c = 0; c < 2; ++c) {
        const int n0 = c * 8;
        // coefficients for this chunk (computed ONCE, reused across 5 directions)
        float4 Ab[8], bu[8];
        #pragma unroll
        for (int k = 0; k < 8; ++k) {
            float4 Bv = Bp[(n0 + k) * 256];
            float A = -__expf(lA[n0 + k]);
            Ab[k].x = __expf(delta.x * A); Ab[k].y = __expf(delta.y * A);
            Ab[k].z = __expf(delta.z * A); Ab[k].w = __expf(delta.w * A);
            bu[k].x = delta.x * Bv.x * u.x; bu[k].y = delta.y * Bv.y * u.y;
            bu[k].z = delta.z * Bv.z * u.z; bu[k].w = delta.w * Bv.w * u.w;
        }
        #pragma unroll
        for (int i = 0; i < NUM_V; ++i) {
            const int src = (i == 3) ? up4 : (i == 4) ? dn4 : hw4;
            const float4* spb = s_prev4 + sbase[i];
            float4* so = outs + sbase[i];
            // batch-issue 16 loads into distinct registers
            float4 s[8], Cv[8];
            #pragma unroll
            for (int k = 0; k < 8; ++k) s[k]  = spb[(n0 + k) * 256 + src];
            #pragma unroll
            for (int k = 0; k < 8; ++k) Cv[k] = Cp[(n0 + k) * 256];
            if (i == 1) {               // vw=+1 -> src col w-1
                #pragma unroll
                for (int k = 0; k < 8; ++k) {
                    float lw = __shfl(s[k].w, ll);
                    float4 q = s[k];
                    s[k].x = lw; s[k].y = q.x; s[k].z = q.y; s[k].w = q.z;
                }
            } else if (i == 2) {        // vw=-1 -> src col w+1
                #pragma unroll
                for (int k = 0; k < 8; ++k) {
                    float rx = __shfl(s[k].x, rl);
                    float4 q = s[k];
                    s[k].x = q.y; s[k].y = q.z; s[k].z = q.w; s[k].w = rx;
                }
            }
            #pragma unroll
            for (int k = 0; k < 8; ++k) {
                float4 sn;
                sn.x = fmaf(Ab[k].x, s[k].x, bu[k].x);
                sn.y = fmaf(Ab[k].y, s[k].y, bu[k].y);
                sn.z = fmaf(Ab[k].z, s[k].z, bu[k].z);
                sn.w = fmaf(Ab[k].w, s[k].w, bu[k].w);
                nt_store4(sn, &so[(n0 + k) * 256 + hw4]);
                y[i].x = fmaf(sn.x, Cv[k].x, y[i].x);
                y[i].y = fmaf(sn.y, Cv[k].y, y[i].y);
                y[i].z = fmaf(sn.z, Cv[k].z, y[i].z);
                y[i].w = fmaf(sn.w, Cv[k].w, y[i].w);
            }
        }
    }

    #pragma unroll
    for (int i = 0; i < NUM_V; ++i) {
        float4 o;
        o.x = fmaf(u.x, Dp, y[i].x); o.y = fmaf(u.y, Dp, y[i].y);
        o.z = fmaf(u.z, Dp, y[i].z); o.w = fmaf(u.w, Dp, y[i].w);
        out4[((b * NUM_V + i) * D_MODEL + d) * 256 + hw4] = o;
    }
}

extern "C" void kernel_launch(void* const* d_in, const int* in_sizes, int n_in,
                              void* d_out, int out_size, void* d_ws, size_t ws_size,
                              hipStream_t stream) {
    const float* u_t     = (const float*)d_in[0];
    const float* s_prev  = (const float*)d_in[1];
    const float* gamma   = (const float*)d_in[2];
    const float* beta    = (const float*)d_in[3];
    const float* w_delta = (const float*)d_in[4];
    const float* b_delta = (const float*)d_in[5];
    const float* w_B     = (const float*)d_in[6];
    const float* w_C     = (const float*)d_in[7];
    const float* log_A   = (const float*)d_in[8];
    const float* D_param = (const float*)d_in[9];
    const float* dt_ptr  = (const float*)d_in[10];
    float* out = (float*)d_out;

    float* unorm = (float*)d_ws;                       // BATCH*96*1024 floats
    float* coef  = unorm + BATCH * D_MODEL * HW;       // BATCH*128*1024 floats

    hipLaunchKernelGGL(gn_kernel, dim3(BATCH * GROUPS), dim3(256), 0, stream,
                       (const float4*)u_t, gamma, beta, (float4*)unorm);
    hipLaunchKernelGGL(conv_kernel, dim3(BATCH * NCOEF), dim3(256), 0, stream,
                       (const float4*)unorm, w_delta, b_delta, w_B, w_C, dt_ptr,
                       (float4*)coef);
    hipLaunchKernelGGL(state_kernel, dim3(BATCH * D_MODEL * 2), dim3(128), 0, stream,
                       (const float4*)u_t, (const float4*)s_prev, (const float4*)coef,
                       log_A, D_param, (float4*)out);
}